// Round 2
// baseline (150.431 us; speedup 1.0000x reference)
//
#include <hip/hip_runtime.h>

typedef __bf16 bf16x8 __attribute__((ext_vector_type(8)));
typedef float f32x4 __attribute__((ext_vector_type(4)));
typedef float f32x16 __attribute__((ext_vector_type(16)));

#define CC 256
#define HH 48
#define WW 64
#define HW (HH * WW)
#define NB 8
#define GW 21

// ---------------------------------------------------------------------------
// Prepass (unchanged from R8): BOTH inputs -> MFMA-fragment PARITY order
//   [b][y][cblk=c>>3][p=x&1][x2=x>>1][c&7] bf16
// in1 scaled by 2^-8 (exact in bf16) to fold the /sumelems.
// ---------------------------------------------------------------------------
__global__ __launch_bounds__(256) void prep_kernel(const float* __restrict__ in1,
                                                   const float* __restrict__ in2,
                                                   unsigned short* __restrict__ o1,
                                                   unsigned short* __restrict__ o2)
{
    __shared__ float lds[CC * 33];
    int blk  = blockIdx.x;
    int sel  = (blk >= 768);
    int blk2 = sel ? blk - 768 : blk;
    int b  = blk2 & 7;
    int st = blk2 >> 3;
    int s0 = st * 32;
    const float* src = sel ? in2 : in1;
    unsigned short* dst = sel ? o2 : o1;
    float scale = sel ? 1.0f : (1.0f / 256.0f);

    int t = threadIdx.x;
    int sidx  = t & 31;
    int cbase = t >> 5;
    const float* sb = src + (size_t)b * CC * HW + s0;
    #pragma unroll
    for (int p = 0; p < 32; ++p) {
        int c = cbase + p * 8;
        lds[c * 33 + sidx] = sb[(size_t)c * HW + sidx] * scale;
    }
    __syncthreads();

    int y  = s0 >> 6;
    int xb = s0 & 63;
    int s  = t & 31;
    int c8 = t >> 5;
    unsigned short* db = dst + (size_t)(b * HH + y) * 32 * 64 * 8;
    int x = xb + s;
    int xoff = (x & 1) * 32 + (x >> 1);
    #pragma unroll
    for (int it = 0; it < 4; ++it) {
        int cblk = it * 8 + c8;
        unsigned dw[4];
        #pragma unroll
        for (int d = 0; d < 4; ++d) {
            unsigned u0 = __builtin_bit_cast(unsigned, lds[(cblk * 8 + 2 * d) * 33 + s]);
            u0 += 0x7fffu + ((u0 >> 16) & 1u);
            unsigned u1 = __builtin_bit_cast(unsigned, lds[(cblk * 8 + 2 * d + 1) * 33 + s]);
            u1 += 0x7fffu + ((u1 >> 16) & 1u);
            dw[d] = (u0 >> 16) | (u1 & 0xffff0000u);
        }
        *(uint4*)(db + ((size_t)cblk * 64 + xoff) * 8) =
            make_uint4(dw[0], dw[1], dw[2], dw[3]);
    }
}

// ---------------------------------------------------------------------------
// Main (R9 rewrite): block = (b, yo-triple, dy-quarter); 384 thr = 6 waves
// = (p in {0,1}) x (a in {0,1,2}). Wave holds A_p(yo0+2a) in 64 VGPRs
// (loaded ONCE -> A global traffic /21 vs R8). Per step t the block stages
// ONE B row (32KB) into LDS via a register ring; the 3 A-rows form a
// parallelogram so each staged B row feeds 3 pairs (dy = d0 + t - a).
// Per pair-half: 16 MFMA 32x32x16 (K=256). Epilogue: per-a shared D^T LDS
// buffer (both parities dump, barrier), then full-line coalesced nontemporal
// stores (x = lane), keeping HBM writes at 1x and L2 clean.
// Grid: 8 b x 16 yo-triples x 4 dy-quarters = 512 blocks = 2/CU exactly.
// Rationale: R8 was co-limited by vL1D port (~2.6MB/CU) and LDS port
// (~3.5MB/CU) at ~17us each; this cuts them to ~0.7MB and ~2.2MB per CU.
// ---------------------------------------------------------------------------
__global__ __launch_bounds__(384, 3) void corr_kernel(const unsigned short* __restrict__ in1F,
                                                      const unsigned short* __restrict__ in2F,
                                                      float* __restrict__ out)
{
    __shared__ unsigned char smem[60416];        // 32KB B stage + 3 x 9216B D^T
    unsigned short* Bl = (unsigned short*)smem;
    float* dtall = (float*)(smem + 32768);

    int blk = blockIdx.x;
    int b   = blk & 7;                           // batch == XCD affinity
    int r   = blk >> 3;                          // 0..63
    int g   = r & 15;                            // yo-triple group
    int dh  = r >> 4;                            // dy quarter 0..3
    int yo0 = (g >> 1) * 6 + (g & 1);            // covers all 48 rows, stride-2 triples
    int d0  = (dh == 0) ? 0 : (5 * dh + 1);      // 0,6,11,16
    int PD  = (dh == 0) ? 6 : 5;
    int NT  = PD + 2;                            // window steps (parallelogram)

    int tid  = threadIdx.x;
    int w    = tid >> 6;                         // 0..5
    int lane = tid & 63;
    int p    = w & 1;                            // parity plane
    int a    = w >> 1;                           // A-row within triple
    int yo   = yo0 + 2 * a;
    int l31  = lane & 31;
    int q2   = lane >> 5;

    // ---- A_p(yo): 16 x bf16x8 = 64 VGPRs, loaded once from global ----
    const unsigned short* arow = in1F + (size_t)(b * HH + yo) * 16384
                               + q2 * 512 + p * 256 + l31 * 8;
    bf16x8 Ar[16];
    #pragma unroll
    for (int kk = 0; kk < 16; ++kk)
        Ar[kk] = *(const bf16x8*)(arow + kk * 1024);

    int ysrc0 = yo0 + 2 * d0 - 20;               // ysrc at t=0; ysrc(t)=ysrc0+2t

    // ---- register staging ring: 32KB row = 2048 uint4 over 384 threads ----
    uint4 sreg[6];
    {
        int ys = ysrc0;
        if (ys >= 0 && ys < HH) {
            const uint4* srcp = (const uint4*)(in2F + (size_t)(b * HH + ys) * 16384);
            #pragma unroll
            for (int i = 0; i < 6; ++i)
                if (i < 5 || tid < 128) sreg[i] = srcp[i * 384 + tid];
        }
    }

    float* dta = dtall + a * 2304;               // [p][32 ce][36] per a
    const unsigned short* bfr = Bl + q2 * 512 + p * 256 + l31 * 8;
    int xe = lane >> 1;
    int pe = lane & 1;

    for (int t = 0; t < NT; ++t) {
        int ys  = ysrc0 + 2 * t;
        bool vs = (ys >= 0 && ys < HH);          // block-uniform

        __syncthreads();                         // B(t-1) reads + D^T(t-1) reads done
        if (vs) {
            uint4* dst = (uint4*)Bl;
            #pragma unroll
            for (int i = 0; i < 6; ++i)
                if (i < 5 || tid < 128) dst[i * 384 + tid] = sreg[i];
        }
        __syncthreads();                         // B(t) visible

        // issue next-row loads early: HBM/L2 latency hides under compute
        if (t + 1 < NT) {
            int ys2 = ys + 2;
            if (ys2 >= 0 && ys2 < HH) {
                const uint4* srcp = (const uint4*)(in2F + (size_t)(b * HH + ys2) * 16384);
                #pragma unroll
                for (int i = 0; i < 6; ++i)
                    if (i < 5 || tid < 128) sreg[i] = srcp[i * 384 + tid];
            }
        }

        int ta   = t - a;
        bool act = (ta >= 0) && (ta < PD);       // this wave has a pair at step t

        if (act && vs) {
            f32x16 acc = (f32x16)(0.0f);
            bf16x8 Bb[2];
            Bb[0] = *(const bf16x8*)bfr;
            #pragma unroll
            for (int kk = 0; kk < 16; ++kk) {
                if (kk < 15)
                    Bb[(kk + 1) & 1] = *(const bf16x8*)(bfr + (kk + 1) * 1024);
                acc = __builtin_amdgcn_mfma_f32_32x32x16_bf16(Ar[kk], Bb[kk & 1], acc, 0, 0, 0);
            }
            // dump D_p^T: dta[p][ce=l31][m], m = rq*8 + q2*4 + s
            #pragma unroll
            for (int rq = 0; rq < 4; ++rq) {
                f32x4 v = { acc[4 * rq], acc[4 * rq + 1],
                            acc[4 * rq + 2], acc[4 * rq + 3] };
                *(f32x4*)(dta + p * 1152 + l31 * 36 + rq * 8 + q2 * 4) = v;
            }
        }
        __syncthreads();                         // both parity dumps visible

        if (act) {
            int dy = d0 + ta;
            float* obase = out + (((size_t)(b * 441 + dy * GW)) * HH + yo) * WW;
            // full-line stores: lane = x = 2*xe + pe; wave p covers jx parity p
            #pragma unroll
            for (int jj = 0; jj < 11; ++jj) {
                int jx = 2 * jj + p;
                if (jx > 20) continue;
                int ce = xe + jx - 10;
                float v = (vs && ce >= 0 && ce < 32)
                        ? dta[pe * 1152 + ce * 36 + xe] : 0.0f;
                __builtin_nontemporal_store(v, obase + (size_t)jx * HW + lane);
            }
        }
    }
}

extern "C" void kernel_launch(void* const* d_in, const int* in_sizes, int n_in,
                              void* d_out, int out_size, void* d_ws, size_t ws_size,
                              hipStream_t stream)
{
    (void)in_sizes; (void)n_in; (void)out_size; (void)ws_size;
    const float* in1 = (const float*)d_in[0];
    const float* in2 = (const float*)d_in[1];
    float* out = (float*)d_out;

    unsigned short* in1F = (unsigned short*)d_ws;                 // 12.6 MB
    unsigned short* in2F = in1F + (size_t)NB * HW * CC;           // 12.6 MB

    prep_kernel<<<dim3(1536), dim3(256), 0, stream>>>(in1, in2, in1F, in2F);
    corr_kernel<<<dim3(512), dim3(384), 0, stream>>>(in1F, in2F, out);
}

// Round 3
// 117.506 us; speedup vs baseline: 1.2802x; 1.2802x over previous
//
#include <hip/hip_runtime.h>

typedef __bf16 bf16x8 __attribute__((ext_vector_type(8)));
typedef float f32x4 __attribute__((ext_vector_type(4)));
typedef float f32x16 __attribute__((ext_vector_type(16)));

#define CC 256
#define HH 48
#define WW 64
#define HW (HH * WW)
#define NB 8
#define GW 21

// ---------------------------------------------------------------------------
// Prepass (unchanged): BOTH inputs -> MFMA-fragment PARITY order
//   [b][y][cblk=c>>3][p=x&1][x2=x>>1][c&7] bf16
// in1 scaled by 2^-8 (exact in bf16) to fold the /sumelems.
// ---------------------------------------------------------------------------
__global__ __launch_bounds__(256) void prep_kernel(const float* __restrict__ in1,
                                                   const float* __restrict__ in2,
                                                   unsigned short* __restrict__ o1,
                                                   unsigned short* __restrict__ o2)
{
    __shared__ float lds[CC * 33];
    int blk  = blockIdx.x;
    int sel  = (blk >= 768);
    int blk2 = sel ? blk - 768 : blk;
    int b  = blk2 & 7;
    int st = blk2 >> 3;
    int s0 = st * 32;
    const float* src = sel ? in2 : in1;
    unsigned short* dst = sel ? o2 : o1;
    float scale = sel ? 1.0f : (1.0f / 256.0f);

    int t = threadIdx.x;
    int sidx  = t & 31;
    int cbase = t >> 5;
    const float* sb = src + (size_t)b * CC * HW + s0;
    #pragma unroll
    for (int p = 0; p < 32; ++p) {
        int c = cbase + p * 8;
        lds[c * 33 + sidx] = sb[(size_t)c * HW + sidx] * scale;
    }
    __syncthreads();

    int y  = s0 >> 6;
    int xb = s0 & 63;
    int s  = t & 31;
    int c8 = t >> 5;
    unsigned short* db = dst + (size_t)(b * HH + y) * 32 * 64 * 8;
    int x = xb + s;
    int xoff = (x & 1) * 32 + (x >> 1);
    #pragma unroll
    for (int it = 0; it < 4; ++it) {
        int cblk = it * 8 + c8;
        unsigned dw[4];
        #pragma unroll
        for (int d = 0; d < 4; ++d) {
            unsigned u0 = __builtin_bit_cast(unsigned, lds[(cblk * 8 + 2 * d) * 33 + s]);
            u0 += 0x7fffu + ((u0 >> 16) & 1u);
            unsigned u1 = __builtin_bit_cast(unsigned, lds[(cblk * 8 + 2 * d + 1) * 33 + s]);
            u1 += 0x7fffu + ((u1 >> 16) & 1u);
            dw[d] = (u0 >> 16) | (u1 & 0xffff0000u);
        }
        *(uint4*)(db + ((size_t)cblk * 64 + xoff) * 8) =
            make_uint4(dw[0], dw[1], dw[2], dw[3]);
    }
}

// ---------------------------------------------------------------------------
// Main (R10): R8's proven 2-barrier block shape + A-reuse via j-PAIRS.
// j=2q and j=2q+1 share the SAME A row yo (ysrc differs by 2), so a block
// stages TWO B rows (64KB LDS) and each of 4 waves computes a j-pair with
// ONE streamed A ring -> A global/L2 traffic halves vs R8 (~260MB -> ~130MB).
// A stays a streamed depth-4 ring (R9's persistent-A spilled; never again).
// acc[2][2] (j x parity), 4 independent MFMA chains/wave for ILP.
// Epilogue: D^T per wave (9216B, reuses B region) done sequentially for the
// two j's. Grid 8b x 88 ysrc0 x 3 jg = 2112, ysrc-major, b = XCD affinity.
// LDS 64KB -> 2 blocks/CU, 8 waves/CU; VGPR ~160 < 256 cap (256,2).
// ---------------------------------------------------------------------------
__global__ __launch_bounds__(256, 2) void corr_kernel(const unsigned short* __restrict__ in1F,
                                                      const unsigned short* __restrict__ in2F,
                                                      float* __restrict__ out)
{
    __shared__ unsigned char smem[65536];        // 2 x 32KB B rows; D^T reuse
    unsigned short* Bl = (unsigned short*)smem;

    int blk = blockIdx.x;
    int b   = blk & 7;                           // batch == XCD affinity
    int r   = blk >> 3;                          // 0..263, ysrc-major
    int yi  = r / 3;
    int jg  = r - yi * 3;                        // 0..2
    int ys0 = yi - 20;                           // B row for j0
    int ys1 = ys0 + 2;                           // B row for j1

    int tid  = threadIdx.x;
    int w    = tid >> 6;
    int lane = tid & 63;
    int q    = jg * 4 + w;                       // j-pair index 0..11
    int yo   = ys0 + 20 - 4 * q;                 // shared A row
    int j0   = 2 * q;
    bool v1  = (q <= 9);                         // j1=2q+1 exists
    bool wvalid = (q <= 10) && (yo >= 0) && (yo < HH);
    bool vs0 = (ys0 >= 0) && (ys0 < HH);
    bool vs1 = (ys1 >= 0) && (ys1 < HH);

    float* orow0 = out + (((size_t)(b * 441 + j0 * GW)) * HH + yo) * WW;
    float* orow1 = orow0 + (size_t)GW * HW;

    if (!vs0 && !vs1) {
        // both B rows OOB -> all owned outputs are zero; exit before barriers
        if (wvalid) {
            #pragma unroll
            for (int jx = 0; jx < GW; ++jx)
                __builtin_nontemporal_store(0.0f, orow0 + (size_t)jx * HW + lane);
            if (v1) {
                #pragma unroll
                for (int jx = 0; jx < GW; ++jx)
                    __builtin_nontemporal_store(0.0f, orow1 + (size_t)jx * HW + lane);
            }
        }
        return;
    }

    int l31 = lane & 31;
    int q2  = lane >> 5;

    // A fragment base (cblk = kk*2+q2, parity p, m = l31): lane-linear 16B
    const unsigned short* arow = in1F
        + ((size_t)(b * HH + (wvalid ? yo : 0)) * 32 + q2) * 512 + (size_t)l31 * 8;

    bf16x8 Ab[4][2], Bb[2][2][2];
    // warm-up A loads before the staging barrier (overlap latency)
    if (wvalid) {
        #pragma unroll
        for (int kr = 0; kr < 3; ++kr)
            #pragma unroll
            for (int p = 0; p < 2; ++p)
                Ab[kr][p] = *(const bf16x8*)(arow + (size_t)kr * 1024 + p * 256);
    }

    // ---- stage the two B rows (fragment order, linear 32KB copies) ----
    {
        uint4* dst = (uint4*)Bl;
        if (vs0) {
            const uint4* s = (const uint4*)(in2F + (size_t)(b * HH + ys0) * 16384);
            #pragma unroll
            for (int i = 0; i < 8; ++i) dst[i * 256 + tid] = s[i * 256 + tid];
        }
        if (vs1) {
            const uint4* s = (const uint4*)(in2F + (size_t)(b * HH + ys1) * 16384);
            #pragma unroll
            for (int i = 0; i < 8; ++i) dst[2048 + i * 256 + tid] = s[i * 256 + tid];
        }
    }
    __syncthreads();

    f32x16 acc[2][2];                            // [jj][parity]
    if (wvalid) {
        const unsigned short* brow = Bl + q2 * 512 + (size_t)l31 * 8;

        #pragma unroll
        for (int jj = 0; jj < 2; ++jj)
            #pragma unroll
            for (int p = 0; p < 2; ++p)
                acc[jj][p] = (f32x16)(0.0f);

        #pragma unroll
        for (int jj = 0; jj < 2; ++jj)
            #pragma unroll
            for (int p = 0; p < 2; ++p)
                Bb[0][jj][p] = *(const bf16x8*)(brow + jj * 16384 + p * 256);

        #pragma unroll
        for (int kk = 0; kk < 16; ++kk) {
            if (kk < 13) {
                #pragma unroll
                for (int p = 0; p < 2; ++p)
                    Ab[(kk + 3) & 3][p] =
                        *(const bf16x8*)(arow + (size_t)(kk + 3) * 1024 + p * 256);
            }
            if (kk < 15) {
                #pragma unroll
                for (int jj = 0; jj < 2; ++jj)
                    #pragma unroll
                    for (int p = 0; p < 2; ++p)
                        Bb[(kk + 1) & 1][jj][p] =
                            *(const bf16x8*)(brow + jj * 16384 + (size_t)(kk + 1) * 1024 + p * 256);
            }
            #pragma unroll
            for (int jj = 0; jj < 2; ++jj)
                #pragma unroll
                for (int p = 0; p < 2; ++p)
                    acc[jj][p] = __builtin_amdgcn_mfma_f32_32x32x16_bf16(
                        Ab[kk & 3][p], Bb[kk & 1][jj][p], acc[jj][p], 0, 0, 0);
        }
    }

    __syncthreads();                             // all B reads done; reuse for D^T
    if (!wvalid) return;

    // Epilogue: per wave, dump+extract D^T for j0 then j1 (private 9216B).
    // 32x32 C layout: col = l31 (n = ce), row = (r&3) + 8*(r>>2) + 4*q2 (m = xe).
    float* dtw = (float*)smem + w * 2304;        // [p][32 ce][36]
    int xe = lane >> 1;
    int pe = lane & 1;
    #pragma unroll
    for (int jj = 0; jj < 2; ++jj) {
        if (jj == 1 && !v1) continue;
        bool vsj = jj ? vs1 : vs0;               // block-uniform
        float* orow = jj ? orow1 : orow0;
        #pragma unroll
        for (int p = 0; p < 2; ++p)
            #pragma unroll
            for (int rq = 0; rq < 4; ++rq) {
                f32x4 v = { acc[jj][p][4 * rq], acc[jj][p][4 * rq + 1],
                            acc[jj][p][4 * rq + 2], acc[jj][p][4 * rq + 3] };
                *(f32x4*)(dtw + (size_t)(p * 32 + l31) * 36 + rq * 8 + q2 * 4) = v;
            }
        #pragma unroll
        for (int jx = 0; jx < GW; ++jx) {
            int ce = xe + jx - 10;               // x = 2*xe+pe, colx = 2*ce+pe
            float val = (vsj && ce >= 0 && ce < 32)
                      ? dtw[(size_t)(pe * 32 + ce) * 36 + xe] : 0.0f;
            __builtin_nontemporal_store(val, orow + (size_t)jx * HW + lane);
        }
    }
}

extern "C" void kernel_launch(void* const* d_in, const int* in_sizes, int n_in,
                              void* d_out, int out_size, void* d_ws, size_t ws_size,
                              hipStream_t stream)
{
    (void)in_sizes; (void)n_in; (void)out_size; (void)ws_size;
    const float* in1 = (const float*)d_in[0];
    const float* in2 = (const float*)d_in[1];
    float* out = (float*)d_out;

    unsigned short* in1F = (unsigned short*)d_ws;                 // 12.6 MB
    unsigned short* in2F = in1F + (size_t)NB * HW * CC;           // 12.6 MB

    prep_kernel<<<dim3(1536), dim3(256), 0, stream>>>(in1, in2, in1F, in2F);
    corr_kernel<<<dim3(NB * 88 * 3), dim3(256), 0, stream>>>(in1F, in2F, out);
}

// Round 4
// 117.037 us; speedup vs baseline: 1.2853x; 1.0040x over previous
//
#include <hip/hip_runtime.h>

typedef __bf16 bf16x8 __attribute__((ext_vector_type(8)));
typedef float f32x4 __attribute__((ext_vector_type(4)));
typedef float f32x16 __attribute__((ext_vector_type(16)));

#define CC 256
#define HH 48
#define WW 64
#define HW (HH * WW)
#define NB 8
#define GW 21

#define GLOAD_LDS16(g, l)                                                     \
    __builtin_amdgcn_global_load_lds(                                         \
        (const __attribute__((address_space(1))) unsigned int*)(g),           \
        (__attribute__((address_space(3))) unsigned int*)(l), 16, 0, 0)

// ---------------------------------------------------------------------------
// Prepass (unchanged): BOTH inputs -> MFMA-fragment PARITY order
//   [b][y][cblk=c>>3][p=x&1][x2=x>>1][c&7] bf16
// in1 scaled by 2^-8 (exact in bf16) to fold the /sumelems.
// ---------------------------------------------------------------------------
__global__ __launch_bounds__(256) void prep_kernel(const float* __restrict__ in1,
                                                   const float* __restrict__ in2,
                                                   unsigned short* __restrict__ o1,
                                                   unsigned short* __restrict__ o2)
{
    __shared__ float lds[CC * 33];
    int blk  = blockIdx.x;
    int sel  = (blk >= 768);
    int blk2 = sel ? blk - 768 : blk;
    int b  = blk2 & 7;
    int st = blk2 >> 3;
    int s0 = st * 32;
    const float* src = sel ? in2 : in1;
    unsigned short* dst = sel ? o2 : o1;
    float scale = sel ? 1.0f : (1.0f / 256.0f);

    int t = threadIdx.x;
    int sidx  = t & 31;
    int cbase = t >> 5;
    const float* sb = src + (size_t)b * CC * HW + s0;
    #pragma unroll
    for (int p = 0; p < 32; ++p) {
        int c = cbase + p * 8;
        lds[c * 33 + sidx] = sb[(size_t)c * HW + sidx] * scale;
    }
    __syncthreads();

    int y  = s0 >> 6;
    int xb = s0 & 63;
    int s  = t & 31;
    int c8 = t >> 5;
    unsigned short* db = dst + (size_t)(b * HH + y) * 32 * 64 * 8;
    int x = xb + s;
    int xoff = (x & 1) * 32 + (x >> 1);
    #pragma unroll
    for (int it = 0; it < 4; ++it) {
        int cblk = it * 8 + c8;
        unsigned dw[4];
        #pragma unroll
        for (int d = 0; d < 4; ++d) {
            unsigned u0 = __builtin_bit_cast(unsigned, lds[(cblk * 8 + 2 * d) * 33 + s]);
            u0 += 0x7fffu + ((u0 >> 16) & 1u);
            unsigned u1 = __builtin_bit_cast(unsigned, lds[(cblk * 8 + 2 * d + 1) * 33 + s]);
            u1 += 0x7fffu + ((u1 >> 16) & 1u);
            dw[d] = (u0 >> 16) | (u1 & 0xffff0000u);
        }
        *(uint4*)(db + ((size_t)cblk * 64 + xoff) * 8) =
            make_uint4(dw[0], dw[1], dw[2], dw[3]);
    }
}

// ---------------------------------------------------------------------------
// Main (R11): R10's j-pair block shape, with the in-loop global latency
// removed. R7/R8/R10 all measured ~23us despite 2x differences in MFMA count
// and A traffic -> the binding constraint was EXPOSED LATENCY of the
// prefetch-3 A ring (~150cy cover vs 200-900cy L2/HBM latency) at 8 waves/CU.
// Changes:
//  1. A ring depth 12 (Ab[12][2], 96 VGPR): 22 loads issued pre-barrier,
//     slots 11..15 issued at kk<5, consumed 7-11 iters (~700-1000cy) later.
//     VGPR ~215 < 256 budget at 2 waves/SIMD (LDS caps occupancy anyway).
//  2. B staged via global_load_lds width-16 (wave-uniform LDS dest,
//     lane-linear global src): no staging VGPRs to collide with the A ring,
//     and the pre-barrier vmcnt(0) drain covers A-prologue completion.
// Grid 8b x 88 ysrc0 x 3 jg = 2112, ysrc-major, b = XCD affinity. LDS 64KB.
// ---------------------------------------------------------------------------
__global__ __launch_bounds__(256, 2) void corr_kernel(const unsigned short* __restrict__ in1F,
                                                      const unsigned short* __restrict__ in2F,
                                                      float* __restrict__ out)
{
    __shared__ unsigned char smem[65536];        // 2 x 32KB B rows; D^T reuse
    unsigned short* Bl = (unsigned short*)smem;

    int blk = blockIdx.x;
    int b   = blk & 7;                           // batch == XCD affinity
    int r   = blk >> 3;                          // 0..263, ysrc-major
    int yi  = r / 3;
    int jg  = r - yi * 3;                        // 0..2
    int ys0 = yi - 20;                           // B row for j0
    int ys1 = ys0 + 2;                           // B row for j1

    int tid  = threadIdx.x;
    int w    = tid >> 6;
    int lane = tid & 63;
    int q    = jg * 4 + w;                       // j-pair index 0..11
    int yo   = ys0 + 20 - 4 * q;                 // shared A row
    int j0   = 2 * q;
    bool v1  = (q <= 9);                         // j1=2q+1 exists
    bool wvalid = (q <= 10) && (yo >= 0) && (yo < HH);
    bool vs0 = (ys0 >= 0) && (ys0 < HH);
    bool vs1 = (ys1 >= 0) && (ys1 < HH);

    float* orow0 = out + (((size_t)(b * 441 + j0 * GW)) * HH + yo) * WW;
    float* orow1 = orow0 + (size_t)GW * HW;

    if (!vs0 && !vs1) {
        // both B rows OOB -> all owned outputs are zero; exit before barriers
        if (wvalid) {
            #pragma unroll
            for (int jx = 0; jx < GW; ++jx)
                __builtin_nontemporal_store(0.0f, orow0 + (size_t)jx * HW + lane);
            if (v1) {
                #pragma unroll
                for (int jx = 0; jx < GW; ++jx)
                    __builtin_nontemporal_store(0.0f, orow1 + (size_t)jx * HW + lane);
            }
        }
        return;
    }

    int l31 = lane & 31;
    int q2  = lane >> 5;

    // A fragment base (cblk = kk*2+q2, parity p, m = l31): lane-linear 16B
    const unsigned short* arow = in1F
        + ((size_t)(b * HH + (wvalid ? yo : 0)) * 32 + q2) * 512 + (size_t)l31 * 8;

    bf16x8 Ab[12][2], Bb[2][2][2];
    // ---- A prologue: slots 0..10 issued before the staging barrier ----
    if (wvalid) {
        #pragma unroll
        for (int kr = 0; kr < 11; ++kr)
            #pragma unroll
            for (int p = 0; p < 2; ++p)
                Ab[kr][p] = *(const bf16x8*)(arow + (size_t)kr * 1024 + p * 256);
    }

    // ---- stage the two B rows via global_load_lds (no VGPR round-trip) ----
    {
        // per-wave 16KB: 8 x 1KB chunks per row; dest wave-uniform,
        // global src lane-linear (+lane*16B added by HW on both sides).
        if (vs0) {
            const unsigned short* s0p = in2F + (size_t)(b * HH + ys0) * 16384
                                       + (size_t)w * 512 + (size_t)lane * 8;
            #pragma unroll
            for (int i = 0; i < 8; ++i)
                GLOAD_LDS16(s0p + (size_t)i * 2048, Bl + (size_t)i * 2048 + w * 512);
        }
        if (vs1) {
            const unsigned short* s1p = in2F + (size_t)(b * HH + ys1) * 16384
                                       + (size_t)w * 512 + (size_t)lane * 8;
            #pragma unroll
            for (int i = 0; i < 8; ++i)
                GLOAD_LDS16(s1p + (size_t)i * 2048,
                            Bl + 16384 + (size_t)i * 2048 + w * 512);
        }
    }
    __syncthreads();                             // vmcnt(0) drain covers A too

    f32x16 acc[2][2];                            // [jj][parity]
    if (wvalid) {
        const unsigned short* brow = Bl + q2 * 512 + (size_t)l31 * 8;

        #pragma unroll
        for (int jj = 0; jj < 2; ++jj)
            #pragma unroll
            for (int p = 0; p < 2; ++p)
                acc[jj][p] = (f32x16)(0.0f);

        #pragma unroll
        for (int jj = 0; jj < 2; ++jj)
            #pragma unroll
            for (int p = 0; p < 2; ++p)
                Bb[0][jj][p] = *(const bf16x8*)(brow + jj * 16384 + p * 256);

        #pragma unroll
        for (int kk = 0; kk < 16; ++kk) {
            if (kk < 5) {                        // A slots 11..15, 7-11 iters ahead
                #pragma unroll
                for (int p = 0; p < 2; ++p)
                    Ab[(kk + 11) % 12][p] =
                        *(const bf16x8*)(arow + (size_t)(kk + 11) * 1024 + p * 256);
            }
            if (kk < 15) {
                #pragma unroll
                for (int jj = 0; jj < 2; ++jj)
                    #pragma unroll
                    for (int p = 0; p < 2; ++p)
                        Bb[(kk + 1) & 1][jj][p] =
                            *(const bf16x8*)(brow + jj * 16384 + (size_t)(kk + 1) * 1024 + p * 256);
            }
            #pragma unroll
            for (int jj = 0; jj < 2; ++jj)
                #pragma unroll
                for (int p = 0; p < 2; ++p)
                    acc[jj][p] = __builtin_amdgcn_mfma_f32_32x32x16_bf16(
                        Ab[kk % 12][p], Bb[kk & 1][jj][p], acc[jj][p], 0, 0, 0);
        }
    }

    __syncthreads();                             // all B reads done; reuse for D^T
    if (!wvalid) return;

    // Epilogue: per wave, dump+extract D^T for j0 then j1 (private 9216B).
    // 32x32 C layout: col = l31 (n = ce), row = (r&3) + 8*(r>>2) + 4*q2 (m = xe).
    float* dtw = (float*)smem + w * 2304;        // [p][32 ce][36]
    int xe = lane >> 1;
    int pe = lane & 1;
    #pragma unroll
    for (int jj = 0; jj < 2; ++jj) {
        if (jj == 1 && !v1) continue;
        bool vsj = jj ? vs1 : vs0;               // block-uniform
        float* orow = jj ? orow1 : orow0;
        #pragma unroll
        for (int p = 0; p < 2; ++p)
            #pragma unroll
            for (int rq = 0; rq < 4; ++rq) {
                f32x4 v = { acc[jj][p][4 * rq], acc[jj][p][4 * rq + 1],
                            acc[jj][p][4 * rq + 2], acc[jj][p][4 * rq + 3] };
                *(f32x4*)(dtw + (size_t)(p * 32 + l31) * 36 + rq * 8 + q2 * 4) = v;
            }
        #pragma unroll
        for (int jx = 0; jx < GW; ++jx) {
            int ce = xe + jx - 10;               // x = 2*xe+pe, colx = 2*ce+pe
            float val = (vsj && ce >= 0 && ce < 32)
                      ? dtw[(size_t)(pe * 32 + ce) * 36 + xe] : 0.0f;
            __builtin_nontemporal_store(val, orow + (size_t)jx * HW + lane);
        }
    }
}

extern "C" void kernel_launch(void* const* d_in, const int* in_sizes, int n_in,
                              void* d_out, int out_size, void* d_ws, size_t ws_size,
                              hipStream_t stream)
{
    (void)in_sizes; (void)n_in; (void)out_size; (void)ws_size;
    const float* in1 = (const float*)d_in[0];
    const float* in2 = (const float*)d_in[1];
    float* out = (float*)d_out;

    unsigned short* in1F = (unsigned short*)d_ws;                 // 12.6 MB
    unsigned short* in2F = in1F + (size_t)NB * HW * CC;           // 12.6 MB

    prep_kernel<<<dim3(1536), dim3(256), 0, stream>>>(in1, in2, in1F, in2F);
    corr_kernel<<<dim3(NB * 88 * 3), dim3(256), 0, stream>>>(in1F, in2F, out);
}